// Round 5
// baseline (636.214 us; speedup 1.0000x reference)
//
#include <hip/hip_runtime.h>
#include <math.h>

#define EMB 128
#define MID 192
#define SEQ 128
#define BATCH 16
#define NPAIR 127
#define KCLS 5
#define EPSF 1e-5f

// ws float-offsets
// WYT: thread-transposed Wy. Thread t = q*128+o (q=k-quarter, o=output) holds
//      WYT[t*64+j] = Wy[q*64+j][o].   (consumed into VGPRs)
// WXX: plain row-major Wxx[k][c], k<128, c<256.  (consumed into LDS)
#define OFF_WYT   0                      // 512*64 = 32768
#define OFF_BY    32768                  // 128
#define OFF_WXX   32896                  // 128*256 = 32768
#define OFF_BXX   65664                  // 256
#define OFF_NODES 65920                  // B*128*128 = 262144
#define OFF_YC    328064                 // B*127*128 = 260096
#define OFF_L0    588160                 // B*127

// ---------------- composite weights ----------------
__global__ void k_comp(const float* __restrict__ W1, const float* __restrict__ b1,
                       const float* __restrict__ W2, const float* __restrict__ b2,
                       const float* __restrict__ W3, const float* __restrict__ b3,
                       const float* __restrict__ W4, const float* __restrict__ b4,
                       float* __restrict__ ws) {
    int tid = blockIdx.x * blockDim.x + threadIdx.x;
    if (tid < 32768) {                    // Wy[k][o], k<256, o<128
        int k = tid >> 7, o = tid & 127;
        float a = 0.f;
        for (int j = 0; j < MID; ++j) a += W1[k*MID+j] * W2[j*EMB+o];
        int q = k >> 6, jj = k & 63;
        ws[OFF_WYT + (size_t)(q*128 + o)*64 + jj] = a;
    } else if (tid < 65536) {             // Wxx[k][c], k<128, c<256
        int t = tid - 32768;
        int k = t >> 8, c = t & 255;
        float a = 0.f;
        for (int j = 0; j < MID; ++j) a += W3[k*MID+j] * W4[j*256+c];
        ws[OFF_WXX + (size_t)k*256 + c] = a;
    } else if (tid < 65536 + 128) {       // by
        int o = tid - 65536;
        float a = b2[o];
        for (int j = 0; j < MID; ++j) a += b1[j] * W2[j*EMB+o];
        ws[OFF_BY + o] = a;
    } else if (tid < 65536 + 128 + 256) { // bxx
        int o = tid - 65536 - 128;
        float a = b4[o];
        for (int j = 0; j < MID; ++j) a += b3[j] * W4[j*256+o];
        ws[OFF_BXX + o] = a;
    }
}

// ---------------- gather embeddings ----------------
__global__ void k_nodes(const int* __restrict__ inp, const float* __restrict__ emb,
                        float* __restrict__ ws) {
    int tid = blockIdx.x * blockDim.x + threadIdx.x;  // B*128*128
    if (tid >= BATCH*SEQ*EMB) return;
    int d = tid & 127;
    int bs = tid >> 7;
    int tok = inp[bs];
    ws[OFF_NODES + tid] = emb[tok*EMB + d];
}

// ---------------- initial 127 pair losses: 16 groups x 16 rows --------------
// Wy in VGPRs (64/thread), Wxx in LDS; 8 pairs per block (4 iters x 2).
__global__ void __launch_bounds__(512, 2) k_init(float* __restrict__ ws) {
    __shared__ float s_wxx[128*256];      // 128 KB
    __shared__ float s_x[2][2*EMB];
    __shared__ float s_red[4][2][EMB];
    __shared__ float s_redx[2][2][256];
    __shared__ float s_y[2][EMB];
    __shared__ float s_by[EMB];
    __shared__ float s_bxx[2*EMB];
    __shared__ float s_ls[2][2];
    int tid = threadIdx.x;
    int b = blockIdx.x >> 4, g = blockIdx.x & 15;
    float4 wy4[16];
    {
        const float4* gw = (const float4*)(ws + OFF_WYT) + (size_t)tid*16;
        #pragma unroll
        for (int i = 0; i < 16; ++i) wy4[i] = gw[i];
        const float4* gx = (const float4*)(ws + OFF_WXX);
        float4* sw = (float4*)s_wxx;
        for (int i = tid; i < 8192; i += 512) sw[i] = gx[i];
    }
    if (tid < EMB) s_by[tid] = ws[OFF_BY + tid];
    if (tid < 2*EMB) s_bxx[tid] = ws[OFF_BXX + tid];
    const float* nodes = ws + OFF_NODES + (size_t)b*SEQ*EMB;
    float* yc = ws + OFF_YC + (size_t)b*NPAIR*EMB;
    int q4 = tid >> 7, o = tid & 127;
    int hh = tid >> 8, c = tid & 255;
    int p_s = tid >> 8, kk = tid & 255;
    __syncthreads();
    for (int it = 0; it < 4; ++it) {
        int base = g*8 + it*2;
        {
            int j = base + p_s;
            int jj = j < NPAIR ? j : NPAIR - 1;
            s_x[p_s][kk] = nodes[(jj + (kk < 128 ? 1 : 0))*EMB + (kk & 127)];
        }
        __syncthreads();
        {
            const float4* sx4 = (const float4*)s_x;
            float a0 = 0.f, a1 = 0.f;
            #pragma unroll
            for (int i = 0; i < 16; ++i) {
                float4 w = wy4[i];
                float4 x0 = sx4[q4*16 + i];
                float4 x1 = sx4[64 + q4*16 + i];
                a0 += x0.x*w.x + x0.y*w.y + x0.z*w.z + x0.w*w.w;
                a1 += x1.x*w.x + x1.y*w.y + x1.z*w.z + x1.w*w.w;
            }
            s_red[q4][0][o] = a0;
            s_red[q4][1][o] = a1;
        }
        __syncthreads();
        if (tid < 256) {
            int p = tid >> 7, oo = tid & 127;
            float yv = s_red[0][p][oo] + s_red[1][p][oo] + s_red[2][p][oo] + s_red[3][p][oo] + s_by[oo];
            s_y[p][oo] = yv;
            int j2 = base + p;
            if (j2 < NPAIR) yc[(size_t)j2*EMB + oo] = yv;
        }
        __syncthreads();
        {
            const float* wp = s_wxx + (hh << 6)*256 + c;
            const float* yp0 = &s_y[0][hh << 6];
            const float* yp1 = &s_y[1][hh << 6];
            float c0 = 0.f, c1 = 0.f;
            #pragma unroll
            for (int j = 0; j < 64; ++j) {
                float w = wp[j*256];
                c0 += yp0[j] * w;
                c1 += yp1[j] * w;
            }
            s_redx[hh][0][c] = c0;
            s_redx[hh][1][c] = c1;
        }
        __syncthreads();
        if (tid < 256) {   // waves 0-3: (pair p2, half h2)
            int w = tid >> 6, lane = tid & 63;
            int p2 = w >> 1, h2 = w & 1;
            int cA = h2*128 + lane, cB = cA + 64;
            float v0 = s_redx[0][p2][cA] + s_redx[1][p2][cA] + s_bxx[cA];
            float v1 = s_redx[0][p2][cB] + s_redx[1][p2][cB] + s_bxx[cB];
            float m = fmaxf(v0, v1);
            for (int s = 32; s; s >>= 1) m = fmaxf(m, __shfl_xor(m, s, 64));
            float se = expf(v0 - m) + expf(v1 - m);
            for (int s = 32; s; s >>= 1) se += __shfl_xor(se, s, 64);
            float lse = m + logf(se);
            float o0 = s_x[p2][cA], o1 = s_x[p2][cB];
            float term = o0*(v0 - lse) + o1*(v1 - lse);
            for (int s = 32; s; s >>= 1) term += __shfl_xor(term, s, 64);
            if (lane == 0) s_ls[p2][h2] = -term;
        }
        __syncthreads();
        if (tid < 2) {
            int j2 = base + tid;
            if (j2 < NPAIR) {
                float l = ((1.f+EPSF)*s_ls[tid][0] + (1.f+EPSF)*s_ls[tid][1]) / (2.f + EPSF);
                ws[OFF_L0 + b*NPAIR + j2] = l;
            }
        }
        __syncthreads();
    }
}

// ---------------- sequential scan: one block (512 thr) per batch row --------
// Wy in VGPRs, Wxx in LDS; nodes / y-cache in global (small coalesced traffic).
__global__ void __launch_bounds__(512, 2) k_seq(float* __restrict__ ws,
                      const float* __restrict__ Wk, const float* __restrict__ bkv,
                      float* __restrict__ out) {
    __shared__ float s_wxx[128*256];      // 128 KB
    __shared__ float s_x[2][2*EMB];
    __shared__ float s_red[4][2][EMB];
    __shared__ float s_redx[2][2][256];
    __shared__ float s_y[2][EMB];
    __shared__ float s_by[EMB];
    __shared__ float s_bxx[2*EMB];
    __shared__ float s_ls[2][2];
    __shared__ float s_loss[NPAIR];
    __shared__ float s_cnt[SEQ];
    __shared__ int   s_nslot[SEQ];
    __shared__ int   s_yslot[NPAIR];
    __shared__ int   s_q[2];
    __shared__ float s_wv[2];
    __shared__ int   s_wi[2];
    __shared__ float s_log[KCLS];

    int tid = threadIdx.x;
    int b = blockIdx.x;
    float4 wy4[16];
    {
        const float4* gw = (const float4*)(ws + OFF_WYT) + (size_t)tid*16;
        #pragma unroll
        for (int i = 0; i < 16; ++i) wy4[i] = gw[i];
        const float4* gx = (const float4*)(ws + OFF_WXX);
        float4* sw = (float4*)s_wxx;
        for (int i = tid; i < 8192; i += 512) sw[i] = gx[i];
    }
    float* nodes = ws + OFF_NODES + (size_t)b*SEQ*EMB;
    float* yc    = ws + OFF_YC    + (size_t)b*NPAIR*EMB;
    if (tid < EMB) s_by[tid] = ws[OFF_BY + tid];
    if (tid < 2*EMB) s_bxx[tid] = ws[OFF_BXX + tid];
    if (tid < NPAIR) { s_loss[tid] = ws[OFF_L0 + b*NPAIR + tid]; s_yslot[tid] = tid; }
    if (tid < SEQ)   { s_cnt[tid] = 1.f; s_nslot[tid] = tid; }
    float acc = 0.f;
    int q4 = tid >> 7, o = tid & 127;
    int hh = tid >> 8, c = tid & 255;
    int p_s = tid >> 8, kk = tid & 255;
    __syncthreads();

    #pragma unroll 1
    for (int t = 0; t < NPAIR; ++t) {
        int L = SEQ - t;
        if (t > 0) {
            {   // stage x for the two affected pairs (coalesced global read)
                int q = s_q[p_s];
                s_x[p_s][kk] = nodes[s_nslot[q + (kk < 128 ? 1 : 0)]*EMB + (kk & 127)];
            }
            __syncthreads();
            // ---- A: Wy partials from register-resident weights
            {
                const float4* sx4 = (const float4*)s_x;
                float a0 = 0.f, a1 = 0.f;
                #pragma unroll
                for (int i = 0; i < 16; ++i) {
                    float4 w = wy4[i];
                    float4 x0 = sx4[q4*16 + i];
                    float4 x1 = sx4[64 + q4*16 + i];
                    a0 += x0.x*w.x + x0.y*w.y + x0.z*w.z + x0.w*w.w;
                    a1 += x1.x*w.x + x1.y*w.y + x1.z*w.z + x1.w*w.w;
                }
                s_red[q4][0][o] = a0;
                s_red[q4][1][o] = a1;
            }
            __syncthreads();
            // ---- B: combine y, write y-cache (global, coalesced 512B x2)
            if (tid < 256) {
                int p = tid >> 7, oo = tid & 127;
                float yv = s_red[0][p][oo] + s_red[1][p][oo] + s_red[2][p][oo] + s_red[3][p][oo] + s_by[oo];
                s_y[p][oo] = yv;
                yc[(size_t)s_yslot[s_q[p]]*EMB + oo] = yv;
            }
            __syncthreads();
            // ---- C: Wxx partials from LDS-resident weights (stride-1, conflict-free)
            {
                const float* wp = s_wxx + (hh << 6)*256 + c;
                const float* yp0 = &s_y[0][hh << 6];
                const float* yp1 = &s_y[1][hh << 6];
                float c0 = 0.f, c1 = 0.f;
                #pragma unroll
                for (int j = 0; j < 64; ++j) {
                    float w = wp[j*256];
                    c0 += yp0[j] * w;
                    c1 += yp1[j] * w;
                }
                s_redx[hh][0][c] = c0;
                s_redx[hh][1][c] = c1;
            }
            __syncthreads();
            // ---- D: softmax + loss dot
            if (tid < 256) {
                int w = tid >> 6, lane = tid & 63;
                int p2 = w >> 1, h2 = w & 1;
                int cA = h2*128 + lane, cB = cA + 64;
                float v0 = s_redx[0][p2][cA] + s_redx[1][p2][cA] + s_bxx[cA];
                float v1 = s_redx[0][p2][cB] + s_redx[1][p2][cB] + s_bxx[cB];
                float m = fmaxf(v0, v1);
                for (int s = 32; s; s >>= 1) m = fmaxf(m, __shfl_xor(m, s, 64));
                float se = expf(v0 - m) + expf(v1 - m);
                for (int s = 32; s; s >>= 1) se += __shfl_xor(se, s, 64);
                float lse = m + logf(se);
                float o0 = s_x[p2][cA], o1 = s_x[p2][cB];
                float term = o0*(v0 - lse) + o1*(v1 - lse);
                for (int s = 32; s; s >>= 1) term += __shfl_xor(term, s, 64);
                if (lane == 0) s_ls[p2][h2] = -term;
            }
            __syncthreads();
        }
        // ---- E: argmin with fused loss update for changed entries
        if (tid < 128) {
            float v = INFINITY;
            if (tid < L-1) {
                v = s_loss[tid];
                if (t > 0 && (tid == s_q[0] || tid == s_q[1])) {
                    int which = (tid == s_q[0]) ? 0 : 1;
                    float n1 = s_cnt[tid+1], n2 = s_cnt[tid];
                    v = ((n1+EPSF)*s_ls[which][0] + (n2+EPSF)*s_ls[which][1]) / (n1+n2+EPSF);
                    s_loss[tid] = v;   // own-slot write
                }
            }
            int ii = tid;
            for (int s = 32; s; s >>= 1) {
                float ov = __shfl_xor(v, s, 64);
                int   oi = __shfl_xor(ii, s, 64);
                if (ov < v || (ov == v && oi < ii)) { v = ov; ii = oi; }
            }
            if ((tid & 63) == 0) { s_wv[tid>>6] = v; s_wi[tid>>6] = ii; }
        }
        __syncthreads();
        // ---- F: select, merge, shift
        float bv0 = s_wv[0], bv1 = s_wv[1];
        int idx = (bv1 < bv0) ? s_wi[1] : s_wi[0];
        if (tid == 0) acc += fminf(bv0, bv1);
        int pos = idx > 0 ? idx - 1 : 0;
        int slotF = s_nslot[pos];
        int ysI   = s_yslot[idx];
        float fcnt = s_cnt[idx] + s_cnt[idx == 0 ? L-1 : idx-1];
        bool doShift = (idx > 0);
        bool shL = doShift && tid >= pos+1 && tid <= L-3;   // loss / yslot
        bool shC = doShift && tid >= pos+1 && tid <= L-2;   // cnt / nslot
        float nl = 0.f, nc = 0.f; int nn = 0, ny = 0;
        if (shL) { nl = s_loss[tid+1]; ny = s_yslot[tid+1]; }
        if (shC) { nc = s_cnt[tid+1];  nn = s_nslot[tid+1]; }
        float fx = (tid < EMB) ? yc[(size_t)ysI*EMB + tid] : 0.f;
        __syncthreads();
        if (tid < EMB) nodes[slotF*EMB + tid] = fx;   // father node <- y of pair
        if (shL) { s_loss[tid] = nl; s_yslot[tid] = ny; }
        if (shC) { s_cnt[tid]  = nc; s_nslot[tid] = nn; }
        if (tid == 0) {
            s_cnt[pos] = fcnt;
            s_q[0] = (pos >= 1) ? pos - 1 : pos;
            s_q[1] = pos;
        }
        __syncthreads();
    }
    // prediction from final root node
    if (tid < KCLS) {
        int slot0 = s_nslot[0];
        float a = bkv[tid];
        for (int k = 0; k < EMB; ++k) a += nodes[slot0*EMB + k] * Wk[k*KCLS + tid];
        s_log[tid] = a;
    }
    __syncthreads();
    if (tid == 0) {
        int best = 0;
        for (int cc = 1; cc < KCLS; ++cc) if (s_log[cc] > s_log[best]) best = cc;
        out[b] = (float)best;
        atomicAdd(&out[BATCH], acc * (1.f/16.f));
    }
}

extern "C" void kernel_launch(void* const* d_in, const int* in_sizes, int n_in,
                              void* d_out, int out_size, void* d_ws, size_t ws_size,
                              hipStream_t stream) {
    const int*   inp = (const int*)d_in[0];
    const float* emb = (const float*)d_in[1];
    const float* W1  = (const float*)d_in[2];
    const float* b1  = (const float*)d_in[3];
    const float* W2  = (const float*)d_in[4];
    const float* b2  = (const float*)d_in[5];
    const float* W3  = (const float*)d_in[6];
    const float* b3  = (const float*)d_in[7];
    const float* W4  = (const float*)d_in[8];
    const float* b4  = (const float*)d_in[9];
    const float* Wk  = (const float*)d_in[10];
    const float* bk  = (const float*)d_in[11];
    float* out = (float*)d_out;
    float* ws  = (float*)d_ws;

    hipMemsetAsync(d_out, 0, (size_t)out_size * sizeof(float), stream);

    k_comp<<<(65920 + 255) / 256, 256, 0, stream>>>(W1, b1, W2, b2, W3, b3, W4, b4, ws);
    k_nodes<<<(BATCH*SEQ*EMB + 255) / 256, 256, 0, stream>>>(inp, emb, ws);
    k_init<<<BATCH * 16, 512, 0, stream>>>(ws);
    k_seq<<<BATCH, 512, 0, stream>>>(ws, Wk, bk, out);
}

// Round 6
// 560.391 us; speedup vs baseline: 1.1353x; 1.1353x over previous
//
#include <hip/hip_runtime.h>
#include <math.h>

#define EMB 128
#define MID 192
#define SEQ 128
#define BATCH 16
#define NPAIR 127
#define KCLS 5
#define EPSF 1e-5f

// ws float-offsets
// WYT: thread-transposed Wy: thread t=q8*128+o (q8=k-eighth, o=output) holds
//      ws[OFF_WYT + t*32 + j] = Wy[q8*32+j][o], j<32.
// WXXT: thread t=h4*256+c holds ws[OFF_WXX + t*32 + j] = Wxx[h4*32+j][c], j<32.
#define OFF_WYT   0                      // 1024*32 = 32768
#define OFF_BY    32768                  // 128
#define OFF_WXX   32896                  // 1024*32 = 32768
#define OFF_BXX   65664                  // 256
#define OFF_NODES 65920                  // B*128*128 = 262144
#define OFF_YC    328064                 // B*127*128 = 260096
#define OFF_L0    588160                 // B*127

// ---------------- composite weights (transposed for per-thread slices) ------
__global__ void k_comp(const float* __restrict__ W1, const float* __restrict__ b1,
                       const float* __restrict__ W2, const float* __restrict__ b2,
                       const float* __restrict__ W3, const float* __restrict__ b3,
                       const float* __restrict__ W4, const float* __restrict__ b4,
                       float* __restrict__ ws) {
    int tid = blockIdx.x * blockDim.x + threadIdx.x;
    if (tid < 32768) {                    // Wy[k][o], k<256, o<128
        int k = tid >> 7, o = tid & 127;
        float a = 0.f;
        for (int j = 0; j < MID; ++j) a += W1[k*MID+j] * W2[j*EMB+o];
        int q8 = k >> 5, jj = k & 31;
        ws[OFF_WYT + ((q8*128 + o) << 5) + jj] = a;
    } else if (tid < 65536) {             // Wxx[k][c], k<128, c<256
        int t = tid - 32768;
        int k = t >> 8, c = t & 255;
        float a = 0.f;
        for (int j = 0; j < MID; ++j) a += W3[k*MID+j] * W4[j*256+c];
        int h4 = k >> 5, jj = k & 31;
        ws[OFF_WXX + ((h4*256 + c) << 5) + jj] = a;
    } else if (tid < 65536 + 128) {       // by
        int o = tid - 65536;
        float a = b2[o];
        for (int j = 0; j < MID; ++j) a += b1[j] * W2[j*EMB+o];
        ws[OFF_BY + o] = a;
    } else if (tid < 65536 + 128 + 256) { // bxx
        int o = tid - 65536 - 128;
        float a = b4[o];
        for (int j = 0; j < MID; ++j) a += b3[j] * W4[j*256+o];
        ws[OFF_BXX + o] = a;
    }
}

// ---------------- gather embeddings ----------------
__global__ void k_nodes(const int* __restrict__ inp, const float* __restrict__ emb,
                        float* __restrict__ ws) {
    int tid = blockIdx.x * blockDim.x + threadIdx.x;  // B*128*128
    if (tid >= BATCH*SEQ*EMB) return;
    int d = tid & 127;
    int bs = tid >> 7;
    int tok = inp[bs];
    ws[OFF_NODES + tid] = emb[tok*EMB + d];
}

// ---------------- initial 127 pair losses: 16 groups x 16 rows --------------
__global__ void __launch_bounds__(1024) k_init(float* __restrict__ ws) {
    __shared__ float s_x[2][2*EMB];
    __shared__ float s_red[8][2][EMB];
    __shared__ float s_redx[4][2][256];
    __shared__ float s_y[2][EMB];
    __shared__ float s_by[EMB];
    __shared__ float s_bxx[2*EMB];
    __shared__ float s_ls[2][2];
    int tid = threadIdx.x;
    int b = blockIdx.x >> 4, g = blockIdx.x & 15;
    float4 wy8[8], wxx8[8];
    {
        const float4* gw = (const float4*)(ws + OFF_WYT) + (size_t)tid*8;
        #pragma unroll
        for (int i = 0; i < 8; ++i) wy8[i] = gw[i];
        const float4* gx = (const float4*)(ws + OFF_WXX) + (size_t)tid*8;
        #pragma unroll
        for (int i = 0; i < 8; ++i) wxx8[i] = gx[i];
    }
    if (tid < EMB) s_by[tid] = ws[OFF_BY + tid];
    if (tid < 2*EMB) s_bxx[tid] = ws[OFF_BXX + tid];
    const float* nodes = ws + OFF_NODES + (size_t)b*SEQ*EMB;
    float* yc = ws + OFF_YC + (size_t)b*NPAIR*EMB;
    int q8 = tid >> 7, o = tid & 127;
    int h4 = tid >> 8, c = tid & 255;
    __syncthreads();
    for (int it = 0; it < 4; ++it) {
        int base = g*8 + it*2;
        if (tid < 512) {   // stage x for the 2 pairs
            int p_s = tid >> 8, kk = tid & 255;
            int j = base + p_s;
            int jj = j < NPAIR ? j : NPAIR - 1;
            s_x[p_s][kk] = nodes[(jj + (kk < 128 ? 1 : 0))*EMB + (kk & 127)];
        }
        __syncthreads();
        {   // A: Wy partials (x broadcast from s_x)
            const float4* sx4 = (const float4*)s_x;
            float a0 = 0.f, a1 = 0.f;
            #pragma unroll
            for (int i = 0; i < 8; ++i) {
                float4 w = wy8[i];
                float4 x0 = sx4[q8*8 + i];
                float4 x1 = sx4[64 + q8*8 + i];
                a0 += x0.x*w.x + x0.y*w.y + x0.z*w.z + x0.w*w.w;
                a1 += x1.x*w.x + x1.y*w.y + x1.z*w.z + x1.w*w.w;
            }
            s_red[q8][0][o] = a0;
            s_red[q8][1][o] = a1;
        }
        __syncthreads();
        if (tid < 256) {   // B: combine y
            int p = tid >> 7, oo = tid & 127;
            float yv = s_by[oo];
            #pragma unroll
            for (int q = 0; q < 8; ++q) yv += s_red[q][p][oo];
            s_y[p][oo] = yv;
            int j2 = base + p;
            if (j2 < NPAIR) yc[(size_t)j2*EMB + oo] = yv;
        }
        __syncthreads();
        {   // C: Wxx partials
            const float4* sy4 = (const float4*)s_y;
            float c0 = 0.f, c1 = 0.f;
            #pragma unroll
            for (int i = 0; i < 8; ++i) {
                float4 w = wxx8[i];
                float4 y0 = sy4[h4*8 + i];
                float4 y1 = sy4[32 + h4*8 + i];
                c0 += y0.x*w.x + y0.y*w.y + y0.z*w.z + y0.w*w.w;
                c1 += y1.x*w.x + y1.y*w.y + y1.z*w.z + y1.w*w.w;
            }
            s_redx[h4][0][c] = c0;
            s_redx[h4][1][c] = c1;
        }
        __syncthreads();
        if (tid < 256) {   // D: softmax + loss dot
            int w = tid >> 6, lane = tid & 63;
            int p2 = w >> 1, h2 = w & 1;
            int cA = h2*128 + lane, cB = cA + 64;
            float v0 = s_redx[0][p2][cA] + s_redx[1][p2][cA] + s_redx[2][p2][cA] + s_redx[3][p2][cA] + s_bxx[cA];
            float v1 = s_redx[0][p2][cB] + s_redx[1][p2][cB] + s_redx[2][p2][cB] + s_redx[3][p2][cB] + s_bxx[cB];
            float m = fmaxf(v0, v1);
            for (int s = 32; s; s >>= 1) m = fmaxf(m, __shfl_xor(m, s, 64));
            float se = expf(v0 - m) + expf(v1 - m);
            for (int s = 32; s; s >>= 1) se += __shfl_xor(se, s, 64);
            float lse = m + logf(se);
            float o0 = s_x[p2][cA], o1 = s_x[p2][cB];
            float term = o0*(v0 - lse) + o1*(v1 - lse);
            for (int s = 32; s; s >>= 1) term += __shfl_xor(term, s, 64);
            if (lane == 0) s_ls[p2][h2] = -term;
        }
        __syncthreads();
        if (tid < 2) {
            int j2 = base + tid;
            if (j2 < NPAIR) {
                float l = ((1.f+EPSF)*s_ls[tid][0] + (1.f+EPSF)*s_ls[tid][1]) / (2.f + EPSF);
                ws[OFF_L0 + b*NPAIR + j2] = l;
            }
        }
        __syncthreads();
    }
}

// ---------------- sequential scan: one block (1024 thr) per batch row -------
// 6 barriers/step; all state LDS-resident; weights in registers (64/thread).
__global__ void __launch_bounds__(1024) k_seq(float* __restrict__ ws,
                      const float* __restrict__ Wk, const float* __restrict__ bkv,
                      float* __restrict__ out) {
    __shared__ float s_nodes[SEQ*EMB];    // 64 KB
    __shared__ float s_yc[NPAIR*EMB];     // 63.5 KB
    __shared__ float s_red[8][2][EMB];    // 8 KB
    __shared__ float s_redx[4][2][256];   // 8 KB
    __shared__ float s_y[2][EMB];
    __shared__ float s_by[EMB];
    __shared__ float s_bxx[2*EMB];
    __shared__ float s_ls[2][2];
    __shared__ float s_loss[2][NPAIR];    // ping-pong
    __shared__ float s_cnt[2][SEQ];
    __shared__ int   s_nslot[2][SEQ];
    __shared__ int   s_yslot[2][NPAIR];
    __shared__ int   s_q[2];
    __shared__ float s_wv[2];
    __shared__ int   s_wi[2];
    __shared__ float s_log[KCLS];

    int tid = threadIdx.x;
    int b = blockIdx.x;
    float4 wy8[8], wxx8[8];
    {
        const float4* gw = (const float4*)(ws + OFF_WYT) + (size_t)tid*8;
        #pragma unroll
        for (int i = 0; i < 8; ++i) wy8[i] = gw[i];
        const float4* gx = (const float4*)(ws + OFF_WXX) + (size_t)tid*8;
        #pragma unroll
        for (int i = 0; i < 8; ++i) wxx8[i] = gx[i];
    }
    {
        const float4* gn = (const float4*)(ws + OFF_NODES + (size_t)b*SEQ*EMB);
        float4* sn = (float4*)s_nodes;
        for (int i = tid; i < SEQ*EMB/4; i += 1024) sn[i] = gn[i];
        const float4* gy = (const float4*)(ws + OFF_YC + (size_t)b*NPAIR*EMB);
        float4* sy = (float4*)s_yc;
        for (int i = tid; i < NPAIR*EMB/4; i += 1024) sy[i] = gy[i];
    }
    if (tid < EMB) s_by[tid] = ws[OFF_BY + tid];
    if (tid < 2*EMB) s_bxx[tid] = ws[OFF_BXX + tid];
    if (tid < NPAIR) { s_loss[0][tid] = ws[OFF_L0 + b*NPAIR + tid]; s_yslot[0][tid] = tid; }
    if (tid < SEQ)   { s_cnt[0][tid] = 1.f; s_nslot[0][tid] = tid; }
    float acc = 0.f;
    int q8 = tid >> 7, o = tid & 127;
    int h4 = tid >> 8, c = tid & 255;
    __syncthreads();

    #pragma unroll 1
    for (int t = 0; t < NPAIR; ++t) {
        int L = SEQ - t;
        int cur = t & 1, nxt = cur ^ 1;
        if (t > 0) {
            {   // ---- A: Wy partials; x read directly from s_nodes (broadcast)
                int r = (q8 < 4) ? 1 : 0;
                int slot0 = s_nslot[cur][s_q[0] + r];
                int slot1 = s_nslot[cur][s_q[1] + r];
                const float4* n4 = (const float4*)s_nodes;
                int sub = (q8 & 3) * 8;
                int base0 = slot0*32 + sub;
                int base1 = slot1*32 + sub;
                float a0 = 0.f, a1 = 0.f;
                #pragma unroll
                for (int i = 0; i < 8; ++i) {
                    float4 w = wy8[i];
                    float4 x0 = n4[base0 + i];
                    float4 x1 = n4[base1 + i];
                    a0 += x0.x*w.x + x0.y*w.y + x0.z*w.z + x0.w*w.w;
                    a1 += x1.x*w.x + x1.y*w.y + x1.z*w.z + x1.w*w.w;
                }
                s_red[q8][0][o] = a0;
                s_red[q8][1][o] = a1;
            }
            __syncthreads();                                   // bar1
            if (tid < 256) {   // ---- B: combine y, write y-cache
                int p = tid >> 7, oo = tid & 127;
                float yv = s_by[oo];
                #pragma unroll
                for (int q = 0; q < 8; ++q) yv += s_red[q][p][oo];
                s_y[p][oo] = yv;
                s_yc[(size_t)s_yslot[cur][s_q[p]]*EMB + oo] = yv;
            }
            __syncthreads();                                   // bar2
            {   // ---- C: Wxx partials
                const float4* sy4 = (const float4*)s_y;
                float c0 = 0.f, c1 = 0.f;
                #pragma unroll
                for (int i = 0; i < 8; ++i) {
                    float4 w = wxx8[i];
                    float4 y0 = sy4[h4*8 + i];
                    float4 y1 = sy4[32 + h4*8 + i];
                    c0 += y0.x*w.x + y0.y*w.y + y0.z*w.z + y0.w*w.w;
                    c1 += y1.x*w.x + y1.y*w.y + y1.z*w.z + y1.w*w.w;
                }
                s_redx[h4][0][c] = c0;
                s_redx[h4][1][c] = c1;
            }
            __syncthreads();                                   // bar3
            if (tid < 256) {   // ---- D: softmax + loss dot
                int w = tid >> 6, lane = tid & 63;
                int p2 = w >> 1, h2 = w & 1;
                int cA = h2*128 + lane, cB = cA + 64;
                float v0 = s_redx[0][p2][cA] + s_redx[1][p2][cA] + s_redx[2][p2][cA] + s_redx[3][p2][cA] + s_bxx[cA];
                float v1 = s_redx[0][p2][cB] + s_redx[1][p2][cB] + s_redx[2][p2][cB] + s_redx[3][p2][cB] + s_bxx[cB];
                float m = fmaxf(v0, v1);
                for (int s = 32; s; s >>= 1) m = fmaxf(m, __shfl_xor(m, s, 64));
                float se = expf(v0 - m) + expf(v1 - m);
                for (int s = 32; s; s >>= 1) se += __shfl_xor(se, s, 64);
                float lse = m + logf(se);
                int slot = s_nslot[cur][s_q[p2] + (h2 == 0 ? 1 : 0)];
                float o0 = s_nodes[slot*EMB + lane];
                float o1 = s_nodes[slot*EMB + 64 + lane];
                float term = o0*(v0 - lse) + o1*(v1 - lse);
                for (int s = 32; s; s >>= 1) term += __shfl_xor(term, s, 64);
                if (lane == 0) s_ls[p2][h2] = -term;
            }
            __syncthreads();                                   // bar4
        }
        // ---- E: fused loss-update + argmin (first-occurrence ties)
        if (tid < 128) {
            float v = INFINITY;
            if (tid < L-1) {
                v = s_loss[cur][tid];
                if (t > 0 && (tid == s_q[0] || tid == s_q[1])) {
                    int which = (tid == s_q[0]) ? 0 : 1;
                    float n1 = s_cnt[cur][tid+1], n2 = s_cnt[cur][tid];
                    v = ((n1+EPSF)*s_ls[which][0] + (n2+EPSF)*s_ls[which][1]) / (n1+n2+EPSF);
                    s_loss[cur][tid] = v;   // own-slot write
                }
            }
            int ii = tid;
            for (int s = 32; s; s >>= 1) {
                float ov = __shfl_xor(v, s, 64);
                int   oi = __shfl_xor(ii, s, 64);
                if (ov < v || (ov == v && oi < ii)) { v = ov; ii = oi; }
            }
            if ((tid & 63) == 0) { s_wv[tid>>6] = v; s_wi[tid>>6] = ii; }
        }
        __syncthreads();                                       // bar5
        // ---- F: select + merge + ping-pong shift (no internal barrier)
        {
            float bv0 = s_wv[0], bv1 = s_wv[1];
            int idx = (bv1 < bv0) ? s_wi[1] : s_wi[0];
            if (tid == 0) acc += fminf(bv0, bv1);
            int pos = idx > 0 ? idx - 1 : 0;
            bool doShift = (idx > 0);
            if (tid < 128) {
                int sC = (doShift && tid >= pos+1 && tid <= L-2) ? 1 : 0;
                float nc = s_cnt[cur][tid + sC];
                int   nn = s_nslot[cur][tid + sC];
                if (tid == pos) {
                    float fcnt = s_cnt[cur][idx] + s_cnt[cur][idx == 0 ? L-1 : idx-1];
                    nc = fcnt;
                }
                s_cnt[nxt][tid] = nc;
                s_nslot[nxt][tid] = nn;
                if (tid < NPAIR) {
                    int sL = (doShift && tid >= pos+1 && tid <= L-3) ? 1 : 0;
                    s_loss[nxt][tid]  = s_loss[cur][tid + sL];
                    s_yslot[nxt][tid] = s_yslot[cur][tid + sL];
                }
            } else if (tid < 256) {
                int d = tid - 128;
                int slotF = s_nslot[cur][pos];
                int ysI   = s_yslot[cur][idx];
                s_nodes[slotF*EMB + d] = s_yc[(size_t)ysI*EMB + d];
            } else if (tid == 256) {
                s_q[0] = (pos >= 1) ? pos - 1 : pos;
                s_q[1] = pos;
            }
        }
        __syncthreads();                                       // bar6
    }
    // prediction from final root node (state in buffer NPAIR&1 = 1)
    if (tid < KCLS) {
        int slot0 = s_nslot[1][0];
        float a = bkv[tid];
        for (int k = 0; k < EMB; ++k) a += s_nodes[slot0*EMB + k] * Wk[k*KCLS + tid];
        s_log[tid] = a;
    }
    __syncthreads();
    if (tid == 0) {
        int best = 0;
        for (int cc = 1; cc < KCLS; ++cc) if (s_log[cc] > s_log[best]) best = cc;
        out[b] = (float)best;
        atomicAdd(&out[BATCH], acc * (1.f/16.f));
    }
}

extern "C" void kernel_launch(void* const* d_in, const int* in_sizes, int n_in,
                              void* d_out, int out_size, void* d_ws, size_t ws_size,
                              hipStream_t stream) {
    const int*   inp = (const int*)d_in[0];
    const float* emb = (const float*)d_in[1];
    const float* W1  = (const float*)d_in[2];
    const float* b1  = (const float*)d_in[3];
    const float* W2  = (const float*)d_in[4];
    const float* b2  = (const float*)d_in[5];
    const float* W3  = (const float*)d_in[6];
    const float* b3  = (const float*)d_in[7];
    const float* W4  = (const float*)d_in[8];
    const float* b4  = (const float*)d_in[9];
    const float* Wk  = (const float*)d_in[10];
    const float* bk  = (const float*)d_in[11];
    float* out = (float*)d_out;
    float* ws  = (float*)d_ws;

    hipMemsetAsync(d_out, 0, (size_t)out_size * sizeof(float), stream);

    k_comp<<<(65920 + 255) / 256, 256, 0, stream>>>(W1, b1, W2, b2, W3, b3, W4, b4, ws);
    k_nodes<<<(BATCH*SEQ*EMB + 255) / 256, 256, 0, stream>>>(inp, emb, ws);
    k_init<<<BATCH * 16, 1024, 0, stream>>>(ws);
    k_seq<<<BATCH, 1024, 0, stream>>>(ws, Wk, bk, out);
}